// Round 1
// baseline (856.748 us; speedup 1.0000x reference)
//
#include <hip/hip_runtime.h>
#include <math.h>

#define D 128
#define H 4
#define CPH 32
#define NEG_SLOPE 0.2f
#define LN_EPS 1e-5f

__device__ __forceinline__ float lrelu(float v) {
    return v > 0.f ? v : NEG_SLOPE * v;
}

// Per-edge scatter: sum x features and count per destination node (col).
__global__ void k_scatter(const float* __restrict__ x, const int* __restrict__ ei,
                          float* __restrict__ sx, int* __restrict__ cnt, int E) {
    int e = blockIdx.x * blockDim.x + threadIdx.x;
    if (e >= E) return;
    int dst = ei[E + e];
    atomicAdd(&sx[dst * 3 + 0], x[e * 3 + 0]);
    atomicAdd(&sx[dst * 3 + 1], x[e * 3 + 1]);
    atomicAdd(&sx[dst * 3 + 2], x[e * 3 + 2]);
    atomicAdd(&cnt[dst], 1);
}

// hm[n,d] = (sx[n] . W_edge[:,d] + cnt*b_edge[d]) / max(cnt,1)
__global__ void k_mean(const float* __restrict__ sx, const int* __restrict__ cnt,
                       const float* __restrict__ W_edge, const float* __restrict__ b_edge,
                       float* __restrict__ hm, int N) {
    int n = blockIdx.x;
    int d = threadIdx.x;
    if (n >= N) return;
    float c = (float)cnt[n];
    float v = sx[n * 3 + 0] * W_edge[0 * D + d]
            + sx[n * 3 + 1] * W_edge[1 * D + d]
            + sx[n * 3 + 2] * W_edge[2 * D + d]
            + c * b_edge[d];
    hm[n * D + d] = v / fmaxf(c, 1.0f);
}

// C[N,128] = A[N,128] @ W[128,128] (+ b). 8 rows per block, 128 threads.
__global__ void k_matmul(const float* __restrict__ A, const float* __restrict__ W,
                         const float* __restrict__ b, float* __restrict__ C, int N) {
    __shared__ float As[8][D];
    int n0 = blockIdx.x * 8;
    int d = threadIdx.x;
    #pragma unroll
    for (int r = 0; r < 8; r++) {
        int n = n0 + r;
        As[r][d] = (n < N) ? A[n * D + d] : 0.f;
    }
    __syncthreads();
    float acc[8] = {0.f, 0.f, 0.f, 0.f, 0.f, 0.f, 0.f, 0.f};
    for (int k = 0; k < D; k++) {
        float wk = W[k * D + d];
        #pragma unroll
        for (int r = 0; r < 8; r++) acc[r] += As[r][k] * wk;
    }
    float bb = b ? b[d] : 0.f;
    #pragma unroll
    for (int r = 0; r < 8; r++) {
        int n = n0 + r;
        if (n < N) C[n * D + d] = acc[r] + bb;
    }
}

// Exclusive scan of cnt[N] -> off[N+1]; single block of 1024 threads.
__global__ void k_scan(const int* __restrict__ cnt, int* __restrict__ off, int N) {
    __shared__ int sm[1024];
    __shared__ int carry;
    if (threadIdx.x == 0) carry = 0;
    __syncthreads();
    for (int base = 0; base < N; base += 1024) {
        int i = base + threadIdx.x;
        int v = (i < N) ? cnt[i] : 0;
        sm[threadIdx.x] = v;
        __syncthreads();
        for (int o = 1; o < 1024; o <<= 1) {
            int t = (threadIdx.x >= (unsigned)o) ? sm[threadIdx.x - o] : 0;
            __syncthreads();
            sm[threadIdx.x] += t;
            __syncthreads();
        }
        int incl = sm[threadIdx.x];
        int c = carry;
        if (i < N) off[i] = c + incl - v;
        __syncthreads();
        if (threadIdx.x == 1023) carry = c + incl;
        __syncthreads();
    }
    if (threadIdx.x == 0) off[N] = carry;
}

// Bucket edges by destination: adj[slot] = src
__global__ void k_fill(const int* __restrict__ ei, const int* __restrict__ off,
                       int* __restrict__ pos, int* __restrict__ adj, int E) {
    int e = blockIdx.x * blockDim.x + threadIdx.x;
    if (e >= E) return;
    int dst = ei[E + e];
    int src = ei[e];
    int slot = off[dst] + atomicAdd(&pos[dst], 1);
    adj[slot] = src;
}

// Attention coefficients: a_s[n,h] = sum_c xh[n,h,c]*att_src[h,c]; same for dst.
__global__ void k_attn(const float* __restrict__ xh, const float* __restrict__ att_src,
                       const float* __restrict__ att_dst,
                       float* __restrict__ a_s, float* __restrict__ a_d, int N) {
    int n = blockIdx.x;
    int d = threadIdx.x;
    if (n >= N) return;
    float v = xh[n * D + d];
    float ps = v * att_src[d];
    float pd = v * att_dst[d];
    #pragma unroll
    for (int o = 16; o > 0; o >>= 1) {
        ps += __shfl_xor(ps, o, 32);
        pd += __shfl_xor(pd, o, 32);
    }
    if ((d & 31) == 0) {
        int hd = d >> 5;
        a_s[n * H + hd] = ps;
        a_d[n * H + hd] = pd;
    }
}

// Fused: segment softmax + aggregate + bias + LayerNorm (+ReLU) + residual.
// One block (128 threads) per node.
__global__ void k_gat(const float* __restrict__ xh, const int* __restrict__ off,
                      const int* __restrict__ adj,
                      const float* __restrict__ a_s, const float* __restrict__ a_d,
                      const float* __restrict__ bias, const float* __restrict__ g,
                      const float* __restrict__ bln,
                      float* __restrict__ h, int N, int do_relu) {
    int n = blockIdx.x;
    int d = threadIdx.x;
    if (n >= N) return;
    int hd = d >> 5;
    int beg = off[n], end = off[n + 1];
    float ad = a_d[n * H + hd];

    // pass 1: segment max (incl. self-loop)
    float e_self = lrelu(a_s[n * H + hd] + ad);
    float m = e_self;
    for (int p = beg; p < end; p++) {
        int s = adj[p];
        m = fmaxf(m, lrelu(a_s[s * H + hd] + ad));
    }

    // pass 2: exp-sum and weighted feature aggregation
    float ex = expf(e_self - m);
    float denom = ex;
    float acc = ex * xh[n * D + d];
    for (int p = beg; p < end; p++) {
        int s = adj[p];
        float e = lrelu(a_s[s * H + hd] + ad);
        float w = expf(e - m);
        denom += w;
        acc += w * xh[s * D + d];
    }
    float out = acc / denom + bias[d];

    // LayerNorm over 128 channels
    __shared__ float sm[D];
    sm[d] = out;
    __syncthreads();
    #pragma unroll
    for (int o = 64; o > 0; o >>= 1) {
        if (d < o) sm[d] += sm[d + o];
        __syncthreads();
    }
    float mu = sm[0] / (float)D;
    __syncthreads();
    float dv = out - mu;
    sm[d] = dv * dv;
    __syncthreads();
    #pragma unroll
    for (int o = 64; o > 0; o >>= 1) {
        if (d < o) sm[d] += sm[d + o];
        __syncthreads();
    }
    float var = sm[0] / (float)D;
    float y = dv * rsqrtf(var + LN_EPS) * g[d] + bln[d];
    if (do_relu) y = fmaxf(y, 0.f);
    h[n * D + d] += y;
}

extern "C" void kernel_launch(void* const* d_in, const int* in_sizes, int n_in,
                              void* d_out, int out_size, void* d_ws, size_t ws_size,
                              hipStream_t stream) {
    const float* x       = (const float*)d_in[0];
    const int*   ei      = (const int*)  d_in[1];
    const float* W_edge  = (const float*)d_in[2];
    const float* b_edge  = (const float*)d_in[3];
    const float* W_node  = (const float*)d_in[4];
    const float* b_node  = (const float*)d_in[5];
    const float* lin_w   = (const float*)d_in[6];
    const float* att_src = (const float*)d_in[7];
    const float* att_dst = (const float*)d_in[8];
    const float* gat_b   = (const float*)d_in[9];
    const float* ln_g    = (const float*)d_in[10];
    const float* ln_b    = (const float*)d_in[11];

    int N = out_size / D;
    int E = in_sizes[1] / 2;

    // workspace carve (all 4-byte types, 256B-aligned)
    char* w = (char*)d_ws;
    auto carve = [&](size_t bytes) {
        void* p = (void*)w;
        w += (bytes + 255) & ~(size_t)255;
        return p;
    };
    float* sx   = (float*)carve((size_t)N * 3 * 4);
    int*   cnt  = (int*)  carve((size_t)N * 4);
    int*   pos  = (int*)  carve((size_t)N * 4);
    int*   off  = (int*)  carve((size_t)(N + 1) * 4);
    int*   adj  = (int*)  carve((size_t)E * 4);
    float* tmp  = (float*)carve((size_t)N * D * 4);
    float* a_s  = (float*)carve((size_t)N * H * 4);
    float* a_d  = (float*)carve((size_t)N * H * 4);

    float* h = (float*)d_out;

    // zero the atomic accumulators (sx, cnt, pos are contiguous)
    hipMemsetAsync(sx, 0, (size_t)N * 3 * 4, stream);
    hipMemsetAsync(cnt, 0, (size_t)N * 4, stream);
    hipMemsetAsync(pos, 0, (size_t)N * 4, stream);

    int tb = 256;
    k_scatter<<<(E + tb - 1) / tb, tb, 0, stream>>>(x, ei, sx, cnt, E);
    k_mean<<<N, D, 0, stream>>>(sx, cnt, W_edge, b_edge, tmp, N);
    k_matmul<<<(N + 7) / 8, D, 0, stream>>>(tmp, W_node, b_node, h, N);
    k_scan<<<1, 1024, 0, stream>>>(cnt, off, N);
    k_fill<<<(E + tb - 1) / tb, tb, 0, stream>>>(ei, off, pos, adj, E);

    for (int i = 0; i < 3; i++) {
        k_matmul<<<(N + 7) / 8, D, 0, stream>>>(h, lin_w + (size_t)i * D * D, nullptr, tmp, N);
        k_attn<<<N, D, 0, stream>>>(tmp, att_src + i * D, att_dst + i * D, a_s, a_d, N);
        k_gat<<<N, D, 0, stream>>>(tmp, off, adj, a_s, a_d,
                                   gat_b + i * D, ln_g + i * D, ln_b + i * D,
                                   h, N, (i < 2) ? 1 : 0);
    }
}

// Round 2
// 579.784 us; speedup vs baseline: 1.4777x; 1.4777x over previous
//
#include <hip/hip_runtime.h>
#include <hip/hip_bf16.h>
#include <math.h>

#define D 128
#define H 4
#define NEG_SLOPE 0.2f
#define LN_EPS 1e-5f
#define CE 64   // edges per softmax chunk in k_gat

__device__ __forceinline__ float lrelu(float v) {
    return v > 0.f ? v : NEG_SLOPE * v;
}

// ---------- edge -> node scatter (sum of 3 raw features + count) ----------
__global__ void k_scatter(const float* __restrict__ x, const int* __restrict__ ei,
                          float* __restrict__ sx, int* __restrict__ cnt, int E) {
    int e = blockIdx.x * blockDim.x + threadIdx.x;
    if (e >= E) return;
    int dst = ei[E + e];
    atomicAdd(&sx[dst * 3 + 0], x[e * 3 + 0]);
    atomicAdd(&sx[dst * 3 + 1], x[e * 3 + 1]);
    atomicAdd(&sx[dst * 3 + 2], x[e * 3 + 2]);
    atomicAdd(&cnt[dst], 1);
}

// hm[n,d] = (sx[n] . W_edge[:,d] + cnt*b_edge[d]) / max(cnt,1)
__global__ void k_mean(const float* __restrict__ sx, const int* __restrict__ cnt,
                       const float* __restrict__ W_edge, const float* __restrict__ b_edge,
                       float* __restrict__ hm, int N) {
    int n = blockIdx.x;
    int d = threadIdx.x;
    if (n >= N) return;
    float c = (float)cnt[n];
    float v = sx[n * 3 + 0] * W_edge[0 * D + d]
            + sx[n * 3 + 1] * W_edge[1 * D + d]
            + sx[n * 3 + 2] * W_edge[2 * D + d]
            + c * b_edge[d];
    hm[n * D + d] = v / fmaxf(c, 1.0f);
}

// ---------- GEMM: C[N,128] = A[N,128] @ W[128,128] ----------
// 64x128 tile per 256-thread block, 4x8 register tile per thread.
// MODE 0: f32 out + bias. MODE 1: bf16 out + fused attention dots (no bias).
template <int MODE>
__global__ __launch_bounds__(256) void k_gemm(
        const float* __restrict__ A, const float* __restrict__ W,
        const float* __restrict__ bias, float* __restrict__ C,
        __hip_bfloat16* __restrict__ xhb, float* __restrict__ a_s,
        float* __restrict__ a_d, const float* __restrict__ att_s,
        const float* __restrict__ att_d, int N) {
    __shared__ float As[64][132];   // pad 132 -> 2-way-max bank aliasing on reads
    int tid = threadIdx.x;
    int n0 = blockIdx.x * 64;

    // stage A tile (64 rows x 128 cols) via float4
    for (int i = tid; i < 64 * 32; i += 256) {
        int r = i >> 5, q = i & 31;
        int n = n0 + r;
        float4 v = make_float4(0.f, 0.f, 0.f, 0.f);
        if (n < N) v = reinterpret_cast<const float4*>(A)[(size_t)n * 32 + q];
        *reinterpret_cast<float4*>(&As[r][q * 4]) = v;
    }
    __syncthreads();

    int tx = tid & 15, ty = tid >> 4;
    int c0 = tx * 8, r0 = ty * 4;
    float acc[4][8];
    #pragma unroll
    for (int r = 0; r < 4; r++)
        #pragma unroll
        for (int c = 0; c < 8; c++) acc[r][c] = 0.f;

    const float4* Wv = reinterpret_cast<const float4*>(W);
    #pragma unroll 4
    for (int k = 0; k < D; k++) {
        float4 w0 = Wv[k * 32 + tx * 2];
        float4 w1 = Wv[k * 32 + tx * 2 + 1];
        #pragma unroll
        for (int r = 0; r < 4; r++) {
            float a = As[r0 + r][k];
            acc[r][0] += a * w0.x; acc[r][1] += a * w0.y;
            acc[r][2] += a * w0.z; acc[r][3] += a * w0.w;
            acc[r][4] += a * w1.x; acc[r][5] += a * w1.y;
            acc[r][6] += a * w1.z; acc[r][7] += a * w1.w;
        }
    }

    if (MODE == 0) {
        float b[8];
        #pragma unroll
        for (int c = 0; c < 8; c++) b[c] = bias[c0 + c];
        #pragma unroll
        for (int r = 0; r < 4; r++) {
            int n = n0 + r0 + r;
            if (n >= N) continue;
            float4 o0 = make_float4(acc[r][0] + b[0], acc[r][1] + b[1],
                                    acc[r][2] + b[2], acc[r][3] + b[3]);
            float4 o1 = make_float4(acc[r][4] + b[4], acc[r][5] + b[5],
                                    acc[r][6] + b[6], acc[r][7] + b[7]);
            reinterpret_cast<float4*>(C)[(size_t)n * 32 + tx * 2] = o0;
            reinterpret_cast<float4*>(C)[(size_t)n * 32 + tx * 2 + 1] = o1;
        }
    } else {
        float ats[8], atd[8];
        #pragma unroll
        for (int c = 0; c < 8; c++) { ats[c] = att_s[c0 + c]; atd[c] = att_d[c0 + c]; }
        #pragma unroll
        for (int r = 0; r < 4; r++) {
            int n = n0 + r0 + r;
            // bf16 pack + store
            union { uint4 v; unsigned short s[8]; } pk;
            #pragma unroll
            for (int c = 0; c < 8; c++) {
                __hip_bfloat16 hb = __float2bfloat16(acc[r][c]);
                pk.s[c] = *reinterpret_cast<unsigned short*>(&hb);
            }
            float ps = 0.f, pd = 0.f;
            #pragma unroll
            for (int c = 0; c < 8; c++) { ps += acc[r][c] * ats[c]; pd += acc[r][c] * atd[c]; }
            ps += __shfl_xor(ps, 1); ps += __shfl_xor(ps, 2);
            pd += __shfl_xor(pd, 1); pd += __shfl_xor(pd, 2);
            if (n < N) {
                *reinterpret_cast<uint4*>(xhb + (size_t)n * D + c0) = pk.v;
                if ((tx & 3) == 0) {
                    a_s[n * H + (tx >> 2)] = ps;
                    a_d[n * H + (tx >> 2)] = pd;
                }
            }
        }
    }
}

// ---------- hierarchical exclusive scan of cnt[N] -> off[N+1] ----------
__global__ void k_scan_part(const int* __restrict__ cnt, int* __restrict__ off,
                            int* __restrict__ bsum, int N) {
    __shared__ int sm[256];
    int i = blockIdx.x * 256 + threadIdx.x;
    int v = (i < N) ? cnt[i] : 0;
    sm[threadIdx.x] = v;
    __syncthreads();
    #pragma unroll
    for (int o = 1; o < 256; o <<= 1) {
        int t = (threadIdx.x >= (unsigned)o) ? sm[threadIdx.x - o] : 0;
        __syncthreads();
        sm[threadIdx.x] += t;
        __syncthreads();
    }
    if (i < N) off[i] = sm[threadIdx.x];       // local inclusive
    if (threadIdx.x == 255) bsum[blockIdx.x] = sm[255];
}

__global__ void k_scan_top(int* __restrict__ bsum, int* __restrict__ off,
                           int NB, int N) {
    __shared__ int sm[256];
    int v = (threadIdx.x < (unsigned)NB) ? bsum[threadIdx.x] : 0;
    sm[threadIdx.x] = v;
    __syncthreads();
    #pragma unroll
    for (int o = 1; o < 256; o <<= 1) {
        int t = (threadIdx.x >= (unsigned)o) ? sm[threadIdx.x - o] : 0;
        __syncthreads();
        sm[threadIdx.x] += t;
        __syncthreads();
    }
    if (threadIdx.x < (unsigned)NB) bsum[threadIdx.x] = sm[threadIdx.x] - v;  // exclusive
    if (threadIdx.x == 255) off[N] = sm[255];
}

__global__ void k_scan_add(const int* __restrict__ cnt, int* __restrict__ off,
                           const int* __restrict__ bsum, int N) {
    int i = blockIdx.x * 256 + threadIdx.x;
    if (i < N) off[i] = off[i] - cnt[i] + bsum[blockIdx.x];
}

// ---------- CSR fill: adj[slot] = src ----------
__global__ void k_fill(const int* __restrict__ ei, const int* __restrict__ off,
                       int* __restrict__ pos, int* __restrict__ adj, int E) {
    int e = blockIdx.x * blockDim.x + threadIdx.x;
    if (e >= E) return;
    int dst = ei[E + e];
    int src = ei[e];
    int slot = off[dst] + atomicAdd(&pos[dst], 1);
    adj[slot] = src;
}

// ---------- fused GAT aggregate + bias + LN (+ReLU) + residual ----------
// One wave (64 lanes) per node; 4 nodes per 256-thread block.
__global__ __launch_bounds__(256) void k_gat2(
        const __hip_bfloat16* __restrict__ xhb, const int* __restrict__ off,
        const int* __restrict__ adj, const float* __restrict__ a_s,
        const float* __restrict__ a_d, const float* __restrict__ bias,
        const float* __restrict__ g, const float* __restrict__ bln,
        float* __restrict__ h, int N, int do_relu) {
    __shared__ float ew_all[4][CE * 4];
    int wid = threadIdx.x >> 6;
    int lane = threadIdx.x & 63;
    int n = blockIdx.x * 4 + wid;
    if (n >= N) return;
    float* ew = ew_all[wid];

    int beg = off[n], end = off[n + 1];
    int deg = end - beg;
    int items = deg + 1;            // + self loop

    int hA = lane & 3;              // phase-A head (fixed per lane)
    int c0 = 2 * lane;              // phase-B channels c0, c0+1
    int hB = lane >> 4;             // head of channel c0

    float adA = a_d[n * H + hA];
    float m = -INFINITY, den = 0.f; // per head class hA (replicated over 16 lanes)
    float acc0 = 0.f, acc1 = 0.f;

    for (int base = 0; base < items; base += CE) {
        int ce = min(CE, items - base);
        // phase A: e values into registers, per-lane max
        float ev[4];
        int nj = 0;
        float lmax = -INFINITY;
        for (int t = lane; t < ce * 4; t += 64) {
            int p = base + (t >> 2);
            int s = (p < deg) ? adj[beg + p] : n;
            float e = lrelu(a_s[s * H + hA] + adA);
            ev[nj++] = e;
            lmax = fmaxf(lmax, e);
        }
        #pragma unroll
        for (int o = 4; o < 64; o <<= 1) lmax = fmaxf(lmax, __shfl_xor(lmax, o));
        float newm = fmaxf(m, lmax);
        float rs = __expf(m - newm);          // m=-inf on first chunk -> 0

        // exp + LDS stash + partial denom
        float lsum = 0.f;
        {
            int j = 0;
            for (int t = lane; t < ce * 4; t += 64) {
                float w = __expf(ev[j++] - newm);
                ew[t] = w;
                lsum += w;
            }
        }
        #pragma unroll
        for (int o = 4; o < 64; o <<= 1) lsum += __shfl_xor(lsum, o);
        den = den * rs + lsum;
        m = newm;

        float rsB = __shfl(rs, hB);           // rescale factor for channel head
        acc0 *= rsB; acc1 *= rsB;

        // make this wave's LDS writes visible to all its lanes
        asm volatile("s_waitcnt lgkmcnt(0)" ::: "memory");

        // phase B: weighted bf16 feature gather
        for (int p = base; p < base + ce; p++) {
            int s = (p < deg) ? adj[beg + p] : n;
            float w = ew[(p - base) * 4 + hB];
            unsigned int u = *reinterpret_cast<const unsigned int*>(
                xhb + (size_t)s * D + c0);
            float f0 = __uint_as_float(u << 16);
            float f1 = __uint_as_float(u & 0xffff0000u);
            acc0 += w * f0;
            acc1 += w * f1;
        }
        asm volatile("s_waitcnt lgkmcnt(0)" ::: "memory");
    }

    float denB = __shfl(den, hB);
    float o0 = acc0 / denB + bias[c0];
    float o1 = acc1 / denB + bias[c0 + 1];

    // LayerNorm across 128 channels, wave-local
    float s1 = o0 + o1;
    #pragma unroll
    for (int o = 1; o < 64; o <<= 1) s1 += __shfl_xor(s1, o);
    float mu = s1 * (1.0f / 128.0f);
    float d0 = o0 - mu, d1 = o1 - mu;
    float s2 = d0 * d0 + d1 * d1;
    #pragma unroll
    for (int o = 1; o < 64; o <<= 1) s2 += __shfl_xor(s2, o);
    float inv = rsqrtf(s2 * (1.0f / 128.0f) + LN_EPS);
    float y0 = d0 * inv * g[c0] + bln[c0];
    float y1 = d1 * inv * g[c0 + 1] + bln[c0 + 1];
    if (do_relu) { y0 = fmaxf(y0, 0.f); y1 = fmaxf(y1, 0.f); }

    float2 hv = *reinterpret_cast<float2*>(h + (size_t)n * D + c0);
    hv.x += y0; hv.y += y1;
    *reinterpret_cast<float2*>(h + (size_t)n * D + c0) = hv;
}

extern "C" void kernel_launch(void* const* d_in, const int* in_sizes, int n_in,
                              void* d_out, int out_size, void* d_ws, size_t ws_size,
                              hipStream_t stream) {
    const float* x       = (const float*)d_in[0];
    const int*   ei      = (const int*)  d_in[1];
    const float* W_edge  = (const float*)d_in[2];
    const float* b_edge  = (const float*)d_in[3];
    const float* W_node  = (const float*)d_in[4];
    const float* b_node  = (const float*)d_in[5];
    const float* lin_w   = (const float*)d_in[6];
    const float* att_src = (const float*)d_in[7];
    const float* att_dst = (const float*)d_in[8];
    const float* gat_b   = (const float*)d_in[9];
    const float* ln_g    = (const float*)d_in[10];
    const float* ln_b    = (const float*)d_in[11];

    int N = out_size / D;
    int E = in_sizes[1] / 2;
    int NB = (N + 255) / 256;

    char* w = (char*)d_ws;
    auto carve = [&](size_t bytes) {
        void* p = (void*)w;
        w += (bytes + 255) & ~(size_t)255;
        return p;
    };
    float* sx   = (float*)carve((size_t)N * 3 * 4);
    int*   cnt  = (int*)  carve((size_t)N * 4);
    int*   pos  = (int*)  carve((size_t)N * 4);
    int*   off  = (int*)  carve((size_t)(N + 1) * 4);
    int*   adj  = (int*)  carve((size_t)E * 4);
    int*   bsum = (int*)  carve((size_t)NB * 4);
    float* tmp  = (float*)carve((size_t)N * D * 4);   // reused as xhb after 1st gemm
    float* a_s  = (float*)carve((size_t)N * H * 4);
    float* a_d  = (float*)carve((size_t)N * H * 4);
    __hip_bfloat16* xhb = (__hip_bfloat16*)tmp;

    float* h = (float*)d_out;

    hipMemsetAsync(sx, 0, (size_t)N * 3 * 4, stream);
    hipMemsetAsync(cnt, 0, (size_t)N * 4, stream);
    hipMemsetAsync(pos, 0, (size_t)N * 4, stream);

    int tb = 256;
    k_scatter<<<(E + tb - 1) / tb, tb, 0, stream>>>(x, ei, sx, cnt, E);
    k_mean<<<N, D, 0, stream>>>(sx, cnt, W_edge, b_edge, tmp, N);
    k_gemm<0><<<(N + 63) / 64, 256, 0, stream>>>(tmp, W_node, b_node, h,
                                                 nullptr, nullptr, nullptr,
                                                 nullptr, nullptr, N);
    k_scan_part<<<NB, 256, 0, stream>>>(cnt, off, bsum, N);
    k_scan_top<<<1, 256, 0, stream>>>(bsum, off, NB, N);
    k_scan_add<<<NB, 256, 0, stream>>>(cnt, off, bsum, N);
    k_fill<<<(E + tb - 1) / tb, tb, 0, stream>>>(ei, off, pos, adj, E);

    for (int i = 0; i < 3; i++) {
        k_gemm<1><<<(N + 63) / 64, 256, 0, stream>>>(
            h, lin_w + (size_t)i * D * D, nullptr, nullptr,
            xhb, a_s, a_d, att_src + i * D, att_dst + i * D, N);
        k_gat2<<<(N + 3) / 4, 256, 0, stream>>>(
            xhb, off, adj, a_s, a_d,
            gat_b + i * D, ln_g + i * D, ln_b + i * D,
            h, N, (i < 2) ? 1 : 0);
    }
}

// Round 3
// 462.847 us; speedup vs baseline: 1.8510x; 1.2526x over previous
//
#include <hip/hip_runtime.h>
#include <hip/hip_bf16.h>
#include <math.h>

#define D 128
#define H 4
#define NEG_SLOPE 0.2f
#define LN_EPS 1e-5f
#define CE 64   // edges per softmax chunk in k_gat2

__device__ __forceinline__ float lrelu(float v) {
    return v > 0.f ? v : NEG_SLOPE * v;
}

// ---------- per-destination in-degree histogram (int atomics only) ----------
__global__ void k_count(const int* __restrict__ ei, int* __restrict__ cnt, int E) {
    int e = blockIdx.x * blockDim.x + threadIdx.x;
    if (e >= E) return;
    atomicAdd(&cnt[ei[E + e]], 1);
}

// ---------- hierarchical exclusive scan of cnt[N] -> off[N+1] ----------
__global__ void k_scan_part(const int* __restrict__ cnt, int* __restrict__ off,
                            int* __restrict__ bsum, int N) {
    __shared__ int sm[256];
    int i = blockIdx.x * 256 + threadIdx.x;
    int v = (i < N) ? cnt[i] : 0;
    sm[threadIdx.x] = v;
    __syncthreads();
    #pragma unroll
    for (int o = 1; o < 256; o <<= 1) {
        int t = (threadIdx.x >= (unsigned)o) ? sm[threadIdx.x - o] : 0;
        __syncthreads();
        sm[threadIdx.x] += t;
        __syncthreads();
    }
    if (i < N) off[i] = sm[threadIdx.x];       // local inclusive
    if (threadIdx.x == 255) bsum[blockIdx.x] = sm[255];
}

__global__ void k_scan_top(int* __restrict__ bsum, int* __restrict__ off,
                           int NB, int N) {
    __shared__ int sm[256];
    int v = (threadIdx.x < (unsigned)NB) ? bsum[threadIdx.x] : 0;
    sm[threadIdx.x] = v;
    __syncthreads();
    #pragma unroll
    for (int o = 1; o < 256; o <<= 1) {
        int t = (threadIdx.x >= (unsigned)o) ? sm[threadIdx.x - o] : 0;
        __syncthreads();
        sm[threadIdx.x] += t;
        __syncthreads();
    }
    if (threadIdx.x < (unsigned)NB) bsum[threadIdx.x] = sm[threadIdx.x] - v;  // exclusive
    if (threadIdx.x == 255) off[N] = sm[255];
}

__global__ void k_scan_add(const int* __restrict__ cnt, int* __restrict__ off,
                           const int* __restrict__ bsum, int N) {
    int i = blockIdx.x * 256 + threadIdx.x;
    if (i < N) off[i] = off[i] - cnt[i] + bsum[blockIdx.x];
}

// ---------- CSR fill: bucket edges by destination, keep src and edge id ----------
__global__ void k_fill(const int* __restrict__ ei, const int* __restrict__ off,
                       int* __restrict__ pos, int* __restrict__ adj_src,
                       int* __restrict__ adj_e, int E) {
    int e = blockIdx.x * blockDim.x + threadIdx.x;
    if (e >= E) return;
    int dst = ei[E + e];
    int slot = off[dst] + atomicAdd(&pos[dst], 1);
    adj_src[slot] = ei[e];
    adj_e[slot] = e;
}

// ---------- per-node gather-sum of raw 3-dim edge features ----------
__global__ void k_xsum(const float* __restrict__ x, const int* __restrict__ off,
                       const int* __restrict__ adj_e, float* __restrict__ sx, int N) {
    int n = blockIdx.x * blockDim.x + threadIdx.x;
    if (n >= N) return;
    int beg = off[n], end = off[n + 1];
    float s0 = 0.f, s1 = 0.f, s2 = 0.f;
    for (int p = beg; p < end; p++) {
        const float* xr = x + (size_t)adj_e[p] * 3;
        s0 += xr[0]; s1 += xr[1]; s2 += xr[2];
    }
    sx[n * 3 + 0] = s0; sx[n * 3 + 1] = s1; sx[n * 3 + 2] = s2;
}

// hm[n,d] = (sx[n] . W_edge[:,d] + cnt*b_edge[d]) / max(cnt,1); cnt from off diff
__global__ void k_mean(const float* __restrict__ sx, const int* __restrict__ off,
                       const float* __restrict__ W_edge, const float* __restrict__ b_edge,
                       float* __restrict__ hm, int N) {
    int n = blockIdx.x;
    int d = threadIdx.x;
    if (n >= N) return;
    float c = (float)(off[n + 1] - off[n]);
    float v = sx[n * 3 + 0] * W_edge[0 * D + d]
            + sx[n * 3 + 1] * W_edge[1 * D + d]
            + sx[n * 3 + 2] * W_edge[2 * D + d]
            + c * b_edge[d];
    hm[n * D + d] = v / fmaxf(c, 1.0f);
}

// ---------- GEMM: C[N,128] = A[N,128] @ W[128,128] ----------
// 64x128 tile per 256-thread block, 4x8 register tile per thread.
// MODE 0: f32 out + bias. MODE 1: bf16 out + fused attention dots (no bias).
template <int MODE>
__global__ __launch_bounds__(256) void k_gemm(
        const float* __restrict__ A, const float* __restrict__ W,
        const float* __restrict__ bias, float* __restrict__ C,
        __hip_bfloat16* __restrict__ xhb, float* __restrict__ a_s,
        float* __restrict__ a_d, const float* __restrict__ att_s,
        const float* __restrict__ att_d, int N) {
    __shared__ float As[64][132];
    int tid = threadIdx.x;
    int n0 = blockIdx.x * 64;

    for (int i = tid; i < 64 * 32; i += 256) {
        int r = i >> 5, q = i & 31;
        int n = n0 + r;
        float4 v = make_float4(0.f, 0.f, 0.f, 0.f);
        if (n < N) v = reinterpret_cast<const float4*>(A)[(size_t)n * 32 + q];
        *reinterpret_cast<float4*>(&As[r][q * 4]) = v;
    }
    __syncthreads();

    int tx = tid & 15, ty = tid >> 4;
    int c0 = tx * 8, r0 = ty * 4;
    float acc[4][8];
    #pragma unroll
    for (int r = 0; r < 4; r++)
        #pragma unroll
        for (int c = 0; c < 8; c++) acc[r][c] = 0.f;

    const float4* Wv = reinterpret_cast<const float4*>(W);
    #pragma unroll 4
    for (int k = 0; k < D; k++) {
        float4 w0 = Wv[k * 32 + tx * 2];
        float4 w1 = Wv[k * 32 + tx * 2 + 1];
        #pragma unroll
        for (int r = 0; r < 4; r++) {
            float a = As[r0 + r][k];
            acc[r][0] += a * w0.x; acc[r][1] += a * w0.y;
            acc[r][2] += a * w0.z; acc[r][3] += a * w0.w;
            acc[r][4] += a * w1.x; acc[r][5] += a * w1.y;
            acc[r][6] += a * w1.z; acc[r][7] += a * w1.w;
        }
    }

    if (MODE == 0) {
        float b[8];
        #pragma unroll
        for (int c = 0; c < 8; c++) b[c] = bias[c0 + c];
        #pragma unroll
        for (int r = 0; r < 4; r++) {
            int n = n0 + r0 + r;
            if (n >= N) continue;
            float4 o0 = make_float4(acc[r][0] + b[0], acc[r][1] + b[1],
                                    acc[r][2] + b[2], acc[r][3] + b[3]);
            float4 o1 = make_float4(acc[r][4] + b[4], acc[r][5] + b[5],
                                    acc[r][6] + b[6], acc[r][7] + b[7]);
            reinterpret_cast<float4*>(C)[(size_t)n * 32 + tx * 2] = o0;
            reinterpret_cast<float4*>(C)[(size_t)n * 32 + tx * 2 + 1] = o1;
        }
    } else {
        float ats[8], atd[8];
        #pragma unroll
        for (int c = 0; c < 8; c++) { ats[c] = att_s[c0 + c]; atd[c] = att_d[c0 + c]; }
        #pragma unroll
        for (int r = 0; r < 4; r++) {
            int n = n0 + r0 + r;
            union { uint4 v; unsigned short s[8]; } pk;
            #pragma unroll
            for (int c = 0; c < 8; c++) {
                __hip_bfloat16 hb = __float2bfloat16(acc[r][c]);
                pk.s[c] = *reinterpret_cast<unsigned short*>(&hb);
            }
            float ps = 0.f, pd = 0.f;
            #pragma unroll
            for (int c = 0; c < 8; c++) { ps += acc[r][c] * ats[c]; pd += acc[r][c] * atd[c]; }
            ps += __shfl_xor(ps, 1); ps += __shfl_xor(ps, 2);
            pd += __shfl_xor(pd, 1); pd += __shfl_xor(pd, 2);
            if (n < N) {
                *reinterpret_cast<uint4*>(xhb + (size_t)n * D + c0) = pk.v;
                if ((tx & 3) == 0) {
                    a_s[n * H + (tx >> 2)] = ps;
                    a_d[n * H + (tx >> 2)] = pd;
                }
            }
        }
    }
}

// ---------- fused GAT aggregate + bias + LN (+ReLU) + residual ----------
// One wave (64 lanes) per node; 4 nodes per 256-thread block.
__global__ __launch_bounds__(256) void k_gat2(
        const __hip_bfloat16* __restrict__ xhb, const int* __restrict__ off,
        const int* __restrict__ adj, const float* __restrict__ a_s,
        const float* __restrict__ a_d, const float* __restrict__ bias,
        const float* __restrict__ g, const float* __restrict__ bln,
        float* __restrict__ h, int N, int do_relu) {
    __shared__ float ew_all[4][CE * 4];
    int wid = threadIdx.x >> 6;
    int lane = threadIdx.x & 63;
    int n = blockIdx.x * 4 + wid;
    if (n >= N) return;
    float* ew = ew_all[wid];

    int beg = off[n], end = off[n + 1];
    int deg = end - beg;
    int items = deg + 1;            // + self loop

    int hA = lane & 3;              // phase-A head (fixed per lane)
    int c0 = 2 * lane;              // phase-B channels c0, c0+1
    int hB = lane >> 4;             // head of channel c0

    float adA = a_d[n * H + hA];
    float m = -INFINITY, den = 0.f;
    float acc0 = 0.f, acc1 = 0.f;

    for (int base = 0; base < items; base += CE) {
        int ce = min(CE, items - base);
        float ev[4];
        int nj = 0;
        float lmax = -INFINITY;
        for (int t = lane; t < ce * 4; t += 64) {
            int p = base + (t >> 2);
            int s = (p < deg) ? adj[beg + p] : n;
            float e = lrelu(a_s[s * H + hA] + adA);
            ev[nj++] = e;
            lmax = fmaxf(lmax, e);
        }
        #pragma unroll
        for (int o = 4; o < 64; o <<= 1) lmax = fmaxf(lmax, __shfl_xor(lmax, o));
        float newm = fmaxf(m, lmax);
        float rs = __expf(m - newm);          // m=-inf on first chunk -> 0

        float lsum = 0.f;
        {
            int j = 0;
            for (int t = lane; t < ce * 4; t += 64) {
                float w = __expf(ev[j++] - newm);
                ew[t] = w;
                lsum += w;
            }
        }
        #pragma unroll
        for (int o = 4; o < 64; o <<= 1) lsum += __shfl_xor(lsum, o);
        den = den * rs + lsum;
        m = newm;

        float rsB = __shfl(rs, hB);
        acc0 *= rsB; acc1 *= rsB;

        asm volatile("s_waitcnt lgkmcnt(0)" ::: "memory");

        #pragma unroll 4
        for (int p = base; p < base + ce; p++) {
            int s = (p < deg) ? adj[beg + p] : n;
            float w = ew[(p - base) * 4 + hB];
            unsigned int u = *reinterpret_cast<const unsigned int*>(
                xhb + (size_t)s * D + c0);
            float f0 = __uint_as_float(u << 16);
            float f1 = __uint_as_float(u & 0xffff0000u);
            acc0 += w * f0;
            acc1 += w * f1;
        }
        asm volatile("s_waitcnt lgkmcnt(0)" ::: "memory");
    }

    float denB = __shfl(den, hB);
    float o0 = acc0 / denB + bias[c0];
    float o1 = acc1 / denB + bias[c0 + 1];

    float s1 = o0 + o1;
    #pragma unroll
    for (int o = 1; o < 64; o <<= 1) s1 += __shfl_xor(s1, o);
    float mu = s1 * (1.0f / 128.0f);
    float d0 = o0 - mu, d1 = o1 - mu;
    float s2 = d0 * d0 + d1 * d1;
    #pragma unroll
    for (int o = 1; o < 64; o <<= 1) s2 += __shfl_xor(s2, o);
    float inv = rsqrtf(s2 * (1.0f / 128.0f) + LN_EPS);
    float y0 = d0 * inv * g[c0] + bln[c0];
    float y1 = d1 * inv * g[c0 + 1] + bln[c0 + 1];
    if (do_relu) { y0 = fmaxf(y0, 0.f); y1 = fmaxf(y1, 0.f); }

    float2 hv = *reinterpret_cast<float2*>(h + (size_t)n * D + c0);
    hv.x += y0; hv.y += y1;
    *reinterpret_cast<float2*>(h + (size_t)n * D + c0) = hv;
}

extern "C" void kernel_launch(void* const* d_in, const int* in_sizes, int n_in,
                              void* d_out, int out_size, void* d_ws, size_t ws_size,
                              hipStream_t stream) {
    const float* x       = (const float*)d_in[0];
    const int*   ei      = (const int*)  d_in[1];
    const float* W_edge  = (const float*)d_in[2];
    const float* b_edge  = (const float*)d_in[3];
    const float* W_node  = (const float*)d_in[4];
    const float* b_node  = (const float*)d_in[5];
    const float* lin_w   = (const float*)d_in[6];
    const float* att_src = (const float*)d_in[7];
    const float* att_dst = (const float*)d_in[8];
    const float* gat_b   = (const float*)d_in[9];
    const float* ln_g    = (const float*)d_in[10];
    const float* ln_b    = (const float*)d_in[11];

    int N = out_size / D;
    int E = in_sizes[1] / 2;
    int NB = (N + 255) / 256;

    char* w = (char*)d_ws;
    auto carve = [&](size_t bytes) {
        void* p = (void*)w;
        w += (bytes + 255) & ~(size_t)255;
        return p;
    };
    float* sx      = (float*)carve((size_t)N * 3 * 4);
    int*   cnt     = (int*)  carve((size_t)N * 4);
    int*   pos     = (int*)  carve((size_t)N * 4);
    int*   off     = (int*)  carve((size_t)(N + 1) * 4);
    int*   adj_src = (int*)  carve((size_t)E * 4);
    int*   adj_e   = (int*)  carve((size_t)E * 4);
    int*   bsum    = (int*)  carve((size_t)NB * 4);
    float* tmp     = (float*)carve((size_t)N * D * 4);
    float* a_s     = (float*)carve((size_t)N * H * 4);
    float* a_d     = (float*)carve((size_t)N * H * 4);
    __hip_bfloat16* xhb = (__hip_bfloat16*)tmp;

    float* h = (float*)d_out;

    hipMemsetAsync(cnt, 0, (size_t)N * 4, stream);
    hipMemsetAsync(pos, 0, (size_t)N * 4, stream);

    int tb = 256;
    k_count<<<(E + tb - 1) / tb, tb, 0, stream>>>(ei, cnt, E);
    k_scan_part<<<NB, 256, 0, stream>>>(cnt, off, bsum, N);
    k_scan_top<<<1, 256, 0, stream>>>(bsum, off, NB, N);
    k_scan_add<<<NB, 256, 0, stream>>>(cnt, off, bsum, N);
    k_fill<<<(E + tb - 1) / tb, tb, 0, stream>>>(ei, off, pos, adj_src, adj_e, E);
    k_xsum<<<(N + tb - 1) / tb, tb, 0, stream>>>(x, off, adj_e, sx, N);
    k_mean<<<N, D, 0, stream>>>(sx, off, W_edge, b_edge, tmp, N);
    k_gemm<0><<<(N + 63) / 64, 256, 0, stream>>>(tmp, W_node, b_node, h,
                                                 nullptr, nullptr, nullptr,
                                                 nullptr, nullptr, N);

    for (int i = 0; i < 3; i++) {
        k_gemm<1><<<(N + 63) / 64, 256, 0, stream>>>(
            h, lin_w + (size_t)i * D * D, nullptr, nullptr,
            xhb, a_s, a_d, att_src + i * D, att_dst + i * D, N);
        k_gat2<<<(N + 3) / 4, 256, 0, stream>>>(
            xhb, off, adj_src, a_s, a_d,
            gat_b + i * D, ln_g + i * D, ln_b + i * D,
            h, N, (i < 2) ? 1 : 0);
    }
}

// Round 4
// 409.539 us; speedup vs baseline: 2.0920x; 1.1302x over previous
//
#include <hip/hip_runtime.h>
#include <hip/hip_bf16.h>
#include <math.h>

#define D 128
#define H 4
#define NEG_SLOPE 0.2f
#define LN_EPS 1e-5f
#define CE 64   // edges per softmax chunk in k_gat3

__device__ __forceinline__ float lrelu(float v) {
    return v > 0.f ? v : NEG_SLOPE * v;
}

// ---------- per-destination in-degree histogram (int atomics only) ----------
__global__ void k_count(const int* __restrict__ ei, int* __restrict__ cnt, int E) {
    int e = blockIdx.x * blockDim.x + threadIdx.x;
    if (e >= E) return;
    atomicAdd(&cnt[ei[E + e]], 1);
}

// ---------- hierarchical exclusive scan of cnt[N] -> off[N+1] ----------
__global__ void k_scan_part(const int* __restrict__ cnt, int* __restrict__ off,
                            int* __restrict__ bsum, int N) {
    __shared__ int sm[256];
    int i = blockIdx.x * 256 + threadIdx.x;
    int v = (i < N) ? cnt[i] : 0;
    sm[threadIdx.x] = v;
    __syncthreads();
    #pragma unroll
    for (int o = 1; o < 256; o <<= 1) {
        int t = (threadIdx.x >= (unsigned)o) ? sm[threadIdx.x - o] : 0;
        __syncthreads();
        sm[threadIdx.x] += t;
        __syncthreads();
    }
    if (i < N) off[i] = sm[threadIdx.x];
    if (threadIdx.x == 255) bsum[blockIdx.x] = sm[255];
}

__global__ void k_scan_top(int* __restrict__ bsum, int* __restrict__ off,
                           int NB, int N) {
    __shared__ int sm[256];
    int v = (threadIdx.x < (unsigned)NB) ? bsum[threadIdx.x] : 0;
    sm[threadIdx.x] = v;
    __syncthreads();
    #pragma unroll
    for (int o = 1; o < 256; o <<= 1) {
        int t = (threadIdx.x >= (unsigned)o) ? sm[threadIdx.x - o] : 0;
        __syncthreads();
        sm[threadIdx.x] += t;
        __syncthreads();
    }
    if (threadIdx.x < (unsigned)NB) bsum[threadIdx.x] = sm[threadIdx.x] - v;
    if (threadIdx.x == 255) off[N] = sm[255];
}

__global__ void k_scan_add(const int* __restrict__ cnt, int* __restrict__ off,
                           const int* __restrict__ bsum, int N) {
    int i = blockIdx.x * 256 + threadIdx.x;
    if (i < N) off[i] = off[i] - cnt[i] + bsum[blockIdx.x];
}

// ---------- CSR fill: adj2[slot] = {src, edge_id} (one 8B store) ----------
__global__ void k_fill(const int* __restrict__ ei, const int* __restrict__ off,
                       int* __restrict__ pos, int2* __restrict__ adj2, int E) {
    int e = blockIdx.x * blockDim.x + threadIdx.x;
    if (e >= E) return;
    int dst = ei[E + e];
    int slot = off[dst] + atomicAdd(&pos[dst], 1);
    adj2[slot] = make_int2(ei[e], e);
}

// ---------- per-node gather-sum of raw 3-dim edge features ----------
__global__ void k_xsum(const float* __restrict__ x, const int* __restrict__ off,
                       const int2* __restrict__ adj2, float* __restrict__ sx, int N) {
    int n = blockIdx.x * blockDim.x + threadIdx.x;
    if (n >= N) return;
    int beg = off[n], end = off[n + 1];
    float s0 = 0.f, s1 = 0.f, s2 = 0.f;
    for (int p = beg; p < end; p++) {
        const float* xr = x + (size_t)adj2[p].y * 3;
        s0 += xr[0]; s1 += xr[1]; s2 += xr[2];
    }
    sx[n * 3 + 0] = s0; sx[n * 3 + 1] = s1; sx[n * 3 + 2] = s2;
}

// ---------- GEMM: C[N,128] = A[N,128] @ W[128,128] ----------
// MODE 1: A explicit, bf16 out + fused attention dots.
// MODE 2: A synthesized from scatter-mean (sx, off, W_edge, b_edge), f32 out + bias.
template <int MODE>
__global__ __launch_bounds__(256) void k_gemm(
        const float* __restrict__ A, const float* __restrict__ W,
        const float* __restrict__ bias, float* __restrict__ C,
        __hip_bfloat16* __restrict__ xhb, float* __restrict__ a_s,
        float* __restrict__ a_d, const float* __restrict__ att_s,
        const float* __restrict__ att_d,
        const float* __restrict__ sx, const int* __restrict__ off,
        const float* __restrict__ W_edge, const float* __restrict__ b_edge,
        int N) {
    __shared__ float As[64][132];
    int tid = threadIdx.x;
    int n0 = blockIdx.x * 64;

    if (MODE == 2) {
        __shared__ float rowf[64][4];
        if (tid < 64) {
            int n = n0 + tid;
            float4 rv = make_float4(0.f, 0.f, 0.f, 0.f);
            if (n < N) {
                rv.x = sx[n * 3 + 0]; rv.y = sx[n * 3 + 1]; rv.z = sx[n * 3 + 2];
                rv.w = (float)(off[n + 1] - off[n]);
            }
            *reinterpret_cast<float4*>(rowf[tid]) = rv;
        }
        __syncthreads();
        int d = tid & 127;
        float we0 = W_edge[d], we1 = W_edge[D + d], we2 = W_edge[2 * D + d];
        float be = b_edge[d];
        for (int r = tid >> 7; r < 64; r += 2) {
            float4 rv = *reinterpret_cast<float4*>(rowf[r]);
            float c = rv.w;
            As[r][d] = (rv.x * we0 + rv.y * we1 + rv.z * we2 + c * be)
                       / fmaxf(c, 1.f);
        }
    } else {
        for (int i = tid; i < 64 * 32; i += 256) {
            int r = i >> 5, q = i & 31;
            int n = n0 + r;
            float4 v = make_float4(0.f, 0.f, 0.f, 0.f);
            if (n < N) v = reinterpret_cast<const float4*>(A)[(size_t)n * 32 + q];
            *reinterpret_cast<float4*>(&As[r][q * 4]) = v;
        }
    }
    __syncthreads();

    int tx = tid & 15, ty = tid >> 4;
    int c0 = tx * 8, r0 = ty * 4;
    float acc[4][8];
    #pragma unroll
    for (int r = 0; r < 4; r++)
        #pragma unroll
        for (int c = 0; c < 8; c++) acc[r][c] = 0.f;

    const float4* Wv = reinterpret_cast<const float4*>(W);
    #pragma unroll 4
    for (int k = 0; k < D; k++) {
        float4 w0 = Wv[k * 32 + tx * 2];
        float4 w1 = Wv[k * 32 + tx * 2 + 1];
        #pragma unroll
        for (int r = 0; r < 4; r++) {
            float a = As[r0 + r][k];
            acc[r][0] += a * w0.x; acc[r][1] += a * w0.y;
            acc[r][2] += a * w0.z; acc[r][3] += a * w0.w;
            acc[r][4] += a * w1.x; acc[r][5] += a * w1.y;
            acc[r][6] += a * w1.z; acc[r][7] += a * w1.w;
        }
    }

    if (MODE == 2) {
        float b[8];
        #pragma unroll
        for (int c = 0; c < 8; c++) b[c] = bias[c0 + c];
        #pragma unroll
        for (int r = 0; r < 4; r++) {
            int n = n0 + r0 + r;
            if (n >= N) continue;
            float4 o0 = make_float4(acc[r][0] + b[0], acc[r][1] + b[1],
                                    acc[r][2] + b[2], acc[r][3] + b[3]);
            float4 o1 = make_float4(acc[r][4] + b[4], acc[r][5] + b[5],
                                    acc[r][6] + b[6], acc[r][7] + b[7]);
            reinterpret_cast<float4*>(C)[(size_t)n * 32 + tx * 2] = o0;
            reinterpret_cast<float4*>(C)[(size_t)n * 32 + tx * 2 + 1] = o1;
        }
    } else {
        float ats[8], atd[8];
        #pragma unroll
        for (int c = 0; c < 8; c++) { ats[c] = att_s[c0 + c]; atd[c] = att_d[c0 + c]; }
        #pragma unroll
        for (int r = 0; r < 4; r++) {
            int n = n0 + r0 + r;
            union { uint4 v; unsigned short s[8]; } pk;
            #pragma unroll
            for (int c = 0; c < 8; c++) {
                __hip_bfloat16 hb = __float2bfloat16(acc[r][c]);
                pk.s[c] = *reinterpret_cast<unsigned short*>(&hb);
            }
            float ps = 0.f, pd = 0.f;
            #pragma unroll
            for (int c = 0; c < 8; c++) { ps += acc[r][c] * ats[c]; pd += acc[r][c] * atd[c]; }
            ps += __shfl_xor(ps, 1); ps += __shfl_xor(ps, 2);
            pd += __shfl_xor(pd, 1); pd += __shfl_xor(pd, 2);
            if (n < N) {
                *reinterpret_cast<uint4*>(xhb + (size_t)n * D + c0) = pk.v;
                if ((tx & 3) == 0) {
                    a_s[n * H + (tx >> 2)] = ps;
                    a_d[n * H + (tx >> 2)] = pd;
                }
            }
        }
    }
}

// ---------- fused GAT aggregate + bias + LN (+ReLU) + residual ----------
// One wave per node; 4 nodes per 256-thread block.
// Lane layout: cl = lane&15 owns channels 8*cl..8*cl+7; sub = lane>>4 picks
// one of 4 edges per iteration (16B dwordx4 gather per lane).
__global__ __launch_bounds__(256) void k_gat3(
        const __hip_bfloat16* __restrict__ xhb, const int* __restrict__ off,
        const int2* __restrict__ adj2, const float* __restrict__ a_s,
        const float* __restrict__ a_d, const float* __restrict__ bias,
        const float* __restrict__ g, const float* __restrict__ bln,
        float* __restrict__ h, int N, int do_relu) {
    __shared__ float ew_all[4][CE * 4];
    __shared__ int si_all[4][CE];
    int wid = threadIdx.x >> 6;
    int lane = threadIdx.x & 63;
    int n = blockIdx.x * 4 + wid;
    if (n >= N) return;
    float* ew = ew_all[wid];
    int* si = si_all[wid];

    int beg = off[n], end = off[n + 1];
    int deg = end - beg;
    int items = deg + 1;            // + self loop

    int hA = lane & 3;              // phase-A head
    int cl = lane & 15;             // channel group: c0 = 8*cl
    int sub = lane >> 4;            // edge sub-slot
    int hb = cl >> 2;               // head of this lane's channels
    int c0 = cl * 8;

    float adA = a_d[n * H + hA];
    float m = -INFINITY, den = 0.f;
    float acc[8];
    #pragma unroll
    for (int c = 0; c < 8; c++) acc[c] = 0.f;

    for (int base = 0; base < items; base += CE) {
        int ce = min(CE, items - base);
        int cep = (ce + 3) & ~3;

        // stage source indices for this chunk (self-loop/pad -> n)
        if (lane < cep) {
            int p = base + lane;
            si[lane] = (p < deg) ? adj2[beg + p].x : n;
        }
        asm volatile("s_waitcnt lgkmcnt(0)" ::: "memory");

        // phase A: attention logits, online max
        float ev[4];
        int nj = 0;
        float lmax = -INFINITY;
        for (int t = lane; t < ce * 4; t += 64) {
            int s = si[t >> 2];
            float e = lrelu(a_s[s * H + hA] + adA);
            ev[nj++] = e;
            lmax = fmaxf(lmax, e);
        }
        #pragma unroll
        for (int o = 4; o < 64; o <<= 1) lmax = fmaxf(lmax, __shfl_xor(lmax, o));
        float newm = fmaxf(m, lmax);
        float rs = __expf(m - newm);          // 0 on first chunk

        float lsum = 0.f;
        {
            int j = 0;
            for (int t = lane; t < cep * 4; t += 64) {
                float w = 0.f;
                if (t < ce * 4) { w = __expf(ev[j++] - newm); lsum += w; }
                ew[t] = w;
            }
        }
        #pragma unroll
        for (int o = 4; o < 64; o <<= 1) lsum += __shfl_xor(lsum, o);
        den = den * rs + lsum;
        m = newm;

        float rsB = __shfl(rs, hb);
        #pragma unroll
        for (int c = 0; c < 8; c++) acc[c] *= rsB;

        asm volatile("s_waitcnt lgkmcnt(0)" ::: "memory");

        // phase B: weighted feature gather, 4 edges per iteration
        for (int p = 0; p < cep; p += 4) {
            int pp = p + sub;
            int s = si[pp];
            float w = ew[pp * 4 + hb];
            uint4 u = *reinterpret_cast<const uint4*>(xhb + (size_t)s * D + c0);
            float f;
            f = __uint_as_float(u.x << 16);        acc[0] += w * f;
            f = __uint_as_float(u.x & 0xffff0000u); acc[1] += w * f;
            f = __uint_as_float(u.y << 16);        acc[2] += w * f;
            f = __uint_as_float(u.y & 0xffff0000u); acc[3] += w * f;
            f = __uint_as_float(u.z << 16);        acc[4] += w * f;
            f = __uint_as_float(u.z & 0xffff0000u); acc[5] += w * f;
            f = __uint_as_float(u.w << 16);        acc[6] += w * f;
            f = __uint_as_float(u.w & 0xffff0000u); acc[7] += w * f;
        }
        asm volatile("s_waitcnt lgkmcnt(0)" ::: "memory");
    }

    float denB = __shfl(den, hb);

    // combine the 4 edge sub-slots: lanes cl, cl+16, cl+32, cl+48
    #pragma unroll
    for (int c = 0; c < 8; c++) {
        acc[c] += __shfl_xor(acc[c], 16);
        acc[c] += __shfl_xor(acc[c], 32);
    }

    float4 b0 = *reinterpret_cast<const float4*>(bias + c0);
    float4 b1 = *reinterpret_cast<const float4*>(bias + c0 + 4);
    float o[8];
    o[0] = acc[0] / denB + b0.x; o[1] = acc[1] / denB + b0.y;
    o[2] = acc[2] / denB + b0.z; o[3] = acc[3] / denB + b0.w;
    o[4] = acc[4] / denB + b1.x; o[5] = acc[5] / denB + b1.y;
    o[6] = acc[6] / denB + b1.z; o[7] = acc[7] / denB + b1.w;

    // LayerNorm (each channel appears 4x across the wave -> divide by 512)
    float s1 = 0.f;
    #pragma unroll
    for (int c = 0; c < 8; c++) s1 += o[c];
    #pragma unroll
    for (int os = 1; os < 64; os <<= 1) s1 += __shfl_xor(s1, os);
    float mu = s1 * (1.0f / 512.0f);
    float s2 = 0.f;
    #pragma unroll
    for (int c = 0; c < 8; c++) { float dv = o[c] - mu; s2 += dv * dv; }
    #pragma unroll
    for (int os = 1; os < 64; os <<= 1) s2 += __shfl_xor(s2, os);
    float inv = rsqrtf(s2 * (1.0f / 512.0f) + LN_EPS);

    if (sub == 0) {
        float4 g0 = *reinterpret_cast<const float4*>(g + c0);
        float4 g1 = *reinterpret_cast<const float4*>(g + c0 + 4);
        float4 l0 = *reinterpret_cast<const float4*>(bln + c0);
        float4 l1 = *reinterpret_cast<const float4*>(bln + c0 + 4);
        float y[8];
        y[0] = (o[0] - mu) * inv * g0.x + l0.x;
        y[1] = (o[1] - mu) * inv * g0.y + l0.y;
        y[2] = (o[2] - mu) * inv * g0.z + l0.z;
        y[3] = (o[3] - mu) * inv * g0.w + l0.w;
        y[4] = (o[4] - mu) * inv * g1.x + l1.x;
        y[5] = (o[5] - mu) * inv * g1.y + l1.y;
        y[6] = (o[6] - mu) * inv * g1.z + l1.z;
        y[7] = (o[7] - mu) * inv * g1.w + l1.w;
        if (do_relu) {
            #pragma unroll
            for (int c = 0; c < 8; c++) y[c] = fmaxf(y[c], 0.f);
        }
        float4 h0 = *reinterpret_cast<float4*>(h + (size_t)n * D + c0);
        float4 h1 = *reinterpret_cast<float4*>(h + (size_t)n * D + c0 + 4);
        h0.x += y[0]; h0.y += y[1]; h0.z += y[2]; h0.w += y[3];
        h1.x += y[4]; h1.y += y[5]; h1.z += y[6]; h1.w += y[7];
        *reinterpret_cast<float4*>(h + (size_t)n * D + c0) = h0;
        *reinterpret_cast<float4*>(h + (size_t)n * D + c0 + 4) = h1;
    }
}

extern "C" void kernel_launch(void* const* d_in, const int* in_sizes, int n_in,
                              void* d_out, int out_size, void* d_ws, size_t ws_size,
                              hipStream_t stream) {
    const float* x       = (const float*)d_in[0];
    const int*   ei      = (const int*)  d_in[1];
    const float* W_edge  = (const float*)d_in[2];
    const float* b_edge  = (const float*)d_in[3];
    const float* W_node  = (const float*)d_in[4];
    const float* b_node  = (const float*)d_in[5];
    const float* lin_w   = (const float*)d_in[6];
    const float* att_src = (const float*)d_in[7];
    const float* att_dst = (const float*)d_in[8];
    const float* gat_b   = (const float*)d_in[9];
    const float* ln_g    = (const float*)d_in[10];
    const float* ln_b    = (const float*)d_in[11];

    int N = out_size / D;
    int E = in_sizes[1] / 2;
    int NB = (N + 255) / 256;

    char* w = (char*)d_ws;
    auto carve = [&](size_t bytes) {
        void* p = (void*)w;
        w += (bytes + 255) & ~(size_t)255;
        return p;
    };
    float* sx   = (float*)carve((size_t)N * 3 * 4);
    int*   cnt  = (int*)  carve((size_t)N * 4);
    int*   pos  = (int*)  carve((size_t)N * 4);
    int*   off  = (int*)  carve((size_t)(N + 1) * 4);
    int2*  adj2 = (int2*) carve((size_t)E * 8);
    int*   bsum = (int*)  carve((size_t)NB * 4);
    float* tmp  = (float*)carve((size_t)N * D * 4);
    float* a_s  = (float*)carve((size_t)N * H * 4);
    float* a_d  = (float*)carve((size_t)N * H * 4);
    __hip_bfloat16* xhb = (__hip_bfloat16*)tmp;

    float* h = (float*)d_out;

    hipMemsetAsync(cnt, 0, (size_t)N * 4, stream);
    hipMemsetAsync(pos, 0, (size_t)N * 4, stream);

    int tb = 256;
    k_count<<<(E + tb - 1) / tb, tb, 0, stream>>>(ei, cnt, E);
    k_scan_part<<<NB, 256, 0, stream>>>(cnt, off, bsum, N);
    k_scan_top<<<1, 256, 0, stream>>>(bsum, off, NB, N);
    k_scan_add<<<NB, 256, 0, stream>>>(cnt, off, bsum, N);
    k_fill<<<(E + tb - 1) / tb, tb, 0, stream>>>(ei, off, pos, adj2, E);
    k_xsum<<<(N + tb - 1) / tb, tb, 0, stream>>>(x, off, adj2, sx, N);
    k_gemm<2><<<(N + 63) / 64, 256, 0, stream>>>(
        nullptr, W_node, b_node, h, nullptr, nullptr, nullptr, nullptr, nullptr,
        sx, off, W_edge, b_edge, N);

    for (int i = 0; i < 3; i++) {
        k_gemm<1><<<(N + 63) / 64, 256, 0, stream>>>(
            h, lin_w + (size_t)i * D * D, nullptr, nullptr,
            xhb, a_s, a_d, att_src + i * D, att_dst + i * D,
            nullptr, nullptr, nullptr, nullptr, N);
        k_gat3<<<(N + 3) / 4, 256, 0, stream>>>(
            xhb, off, adj2, a_s, a_d,
            gat_b + i * D, ln_g + i * D, ln_b + i * D,
            h, N, (i < 2) ? 1 : 0);
    }
}